// Round 9
// baseline (399.794 us; speedup 1.0000x reference)
//
#include <hip/hip_runtime.h>

typedef short bf16x8 __attribute__((ext_vector_type(8)));
typedef float f32x4 __attribute__((ext_vector_type(4)));
typedef float f32x16 __attribute__((ext_vector_type(16)));
typedef unsigned u32;
typedef unsigned short u16;
typedef unsigned u32x4v __attribute__((ext_vector_type(4)));
typedef unsigned u32x2v __attribute__((ext_vector_type(2)));

union UV { u32x4v u; bf16x8 v; };

__device__ __forceinline__ u16 f2bf(float f){          // RNE fp32->bf16 (cold paths)
  u32 u = __float_as_uint(f);
  u += 0x7FFFu + ((u>>16)&1u);
  return (u16)(u>>16);
}
// hot-path pair conversion: single v_cvt_pk_bf16_f32 (no builtin on gfx950 -> inline asm, T12 recipe)
__device__ __forceinline__ u32 pack2(float lo, float hi){
  u32 r;
  asm("v_cvt_pk_bf16_f32 %0, %1, %2" : "=v"(r) : "v"(lo), "v"(hi));
  return r;
}

#define LOG2E 1.4426950408889634f

// ---------------- K_prep: fused prologue (q_scaled | bias | weight cvt) ----------------
__global__ void k_prep(const float* __restrict__ emb, const float* __restrict__ q_w,
                       const float* __restrict__ q_b, u16* __restrict__ q_s,
                       const float* __restrict__ rpb, float* __restrict__ bias,
                       const float* __restrict__ kv_w, const float* __restrict__ proj_w,
                       u32* __restrict__ kvb, u32* __restrict__ pjb){
  const int blk = blockIdx.x, tid = threadIdx.x;
  if(blk < 64){
    const int n = blk, d = tid;
    const float4* er = (const float4*)(emb + n*256);
    const float4* wr = (const float4*)(q_w + d*256);
    float acc = 0.f;
    for(int c=0;c<64;++c){
      float4 e = er[c], w = wr[c];
      acc += e.x*w.x + e.y*w.y + e.z*w.z + e.w*w.w;
    }
    acc += q_b[d];
    q_s[n*256 + d] = f2bf(acc * (0.17677669529663687f * LOG2E));   // 32^-0.5 * log2e
  } else if(blk < 192){
    const int o = (blk-64)*256 + tid;          // 32768
    const int h = o>>12, n = (o>>6)&63, m = o&63;
    const int idx = ((n>>3)-(m>>3)+7)*15 + ((n&7)-(m&7)+7);
    bias[o] = rpb[idx*8 + h] * LOG2E;
  } else {
    const int i = (blk-192)*256 + tid;         // 98304
    if(i < 65536) kvb[i] = pack2(kv_w[2*i], kv_w[2*i+1]);
    else { int j = i - 65536; pjb[j] = pack2(proj_w[2*j], proj_w[2*j+1]); }
  }
}

// stage one 64x256 fp32 window -> RA as bf16 (swizzled byte ^= ((n&7)<<4))
__device__ __forceinline__ void stage_x(const float* __restrict__ xb, char* RA, int tid){
  #pragma unroll
  for(int i=0;i<4;++i){
    int p = i*512 + tid;                 // 16B-pair index 0..2047
    int n = p>>5;                        // token row 0..63
    int c4 = (2*p)&63;                   // f4 index within row (even)
    const float4* gp = (const float4*)(xb + (n>>3)*32768 + (n&7)*256 + c4*4);
    float4 lo = gp[0], hh = gp[1];
    u32x4v d = { pack2(lo.x,lo.y), pack2(lo.z,lo.w), pack2(hh.x,hh.y), pack2(hh.z,hh.w) };
    *(u32x4v*)(RA + ((p*16) ^ ((n&7)<<4))) = d;
  }
}

// ---------------- one window, straight-line (inlined twice — NO backedge, R7 lesson) ----------------
// RA (32KB): x_bf16[64][256] swz -> k[64][256] swz -> (free after kf preload) -> next window's x
// RB (32KB): vT[8h][32 e][64 m] swz -> ao[8h][64 n][32 e] swz (own-head chunk)
template<bool STAGE_NEXT>
__device__ __forceinline__ void do_window(int bw, const float* __restrict__ xn,
    char* RA, char* RB, const u16* __restrict__ kvw, const float* __restrict__ kv_b,
    const u16* __restrict__ q_s, const float* __restrict__ bias, const u16* __restrict__ pjw,
    const float* __restrict__ proj_b, float* __restrict__ out,
    int tid, int w, int g, int li, int l31, int hi, int oddl){
  const int h = w;

  // ---------- KV GEMM: wave w -> output cols w*64..w*64+63 (reads RA x-image) ----------
  f32x4 acc[4][4];
  #pragma unroll
  for(int ct=0;ct<4;++ct){
    float bv = kv_b[w*64 + ct*16 + li];
    #pragma unroll
    for(int rt=0;rt<4;++rt) acc[rt][ct] = (f32x4){bv,bv,bv,bv};
  }
  {
    const u16* wbase = kvw + (w*64 + li)*256 + g*8;   // + ct*4096 + ks*32
    bf16x8 bcur[4];
    #pragma unroll
    for(int ct=0;ct<4;++ct) bcur[ct] = *(const bf16x8*)(wbase + ct*4096);
    __builtin_amdgcn_s_setprio(1);
    #pragma unroll
    for(int ks=0;ks<8;++ks){
      bf16x8 a[4];
      #pragma unroll
      for(int rt=0;rt<4;++rt){
        int n = rt*16 + li;
        a[rt] = *(const bf16x8*)(RA + ((n*512 + ks*64 + g*16) ^ ((n&7)<<4)));
      }
      #pragma unroll
      for(int ct=0;ct<4;++ct){
        #pragma unroll
        for(int rt=0;rt<4;++rt)
          acc[rt][ct] = __builtin_amdgcn_mfma_f32_16x16x32_bf16(a[rt], bcur[ct], acc[rt][ct], 0,0,0);
        if(ks<7) bcur[ct] = *(const bf16x8*)(wbase + ct*4096 + (ks+1)*32);  // load-after-use prefetch
      }
    }
    __builtin_amdgcn_s_setprio(0);
  }
  __syncthreads();   // x image dead -> RA free for k

  // ---------- merged publish: waves 0..3 -> k into RA | waves 4..7 -> vT into RB ----------
  if(w < 4){
    #pragma unroll
    for(int ct=0;ct<4;++ct){
      int colp = w*64 + ct*16 + (li & ~1);   // even col of the pair
      #pragma unroll
      for(int rt=0;rt<4;++rt){
        float v0=acc[rt][ct][0], v1=acc[rt][ct][1], v2=acc[rt][ct][2], v3=acc[rt][ct][3];
        float o0=__shfl_xor(v0,1), o1=__shfl_xor(v1,1), o2=__shfl_xor(v2,1), o3=__shfl_xor(v3,1);
        u32 d0 = oddl ? pack2(o2,v2) : pack2(v0,o0);
        u32 d1 = oddl ? pack2(o3,v3) : pack2(v1,o1);
        int row0 = rt*16 + 4*g + (oddl ? 2 : 0);
        *(u32*)(RA + ((row0*512     + colp*2) ^ ((row0&7)<<4)))     = d0;
        *(u32*)(RA + (((row0+1)*512 + colp*2) ^ (((row0+1)&7)<<4))) = d1;
      }
    }
  } else {
    #pragma unroll
    for(int ct=0;ct<4;++ct){
      int c2 = (w-4)*64 + ct*16 + li;     // 0..255
      int hv = c2>>5, e = c2&31;
      #pragma unroll
      for(int rt=0;rt<4;++rt){
        u32x2v d;
        d[0] = pack2(acc[rt][ct][0], acc[rt][ct][1]);
        d[1] = pack2(acc[rt][ct][2], acc[rt][ct][3]);
        int m0 = rt*16 + 4*g;
        *(u32x2v*)(RB + (((hv*32 + e)*128 + m0*2) ^ ((e&7)<<4))) = d;
      }
    }
  }
  __syncthreads();   // k and vT visible

  // ---------- fragment preload: qf (global), kf (RA) ----------
  bf16x8 qf[2][2], kf[2][2];
  #pragma unroll
  for(int nt=0;nt<2;++nt)
    #pragma unroll
    for(int ks=0;ks<2;++ks)
      qf[nt][ks] = *(const bf16x8*)(q_s + (nt*32 + l31)*256 + h*32 + ks*16 + hi*8);
  #pragma unroll
  for(int mt=0;mt<2;++mt)
    #pragma unroll
    for(int ks=0;ks<2;++ks){
      int row = mt*32 + l31;
      kf[mt][ks] = *(const bf16x8*)(RA + ((row*512 + (h*32 + ks*16 + hi*8)*2) ^ ((row&7)<<4)));
    }
  __syncthreads();   // k consumed into regs -> RA free (for next window's x)

  // ---------- attention: S^T = K·Q^T (32x32 tiles), softmax in log2 units ----------
  f32x16 S[2][2];
  #pragma unroll
  for(int mt=0;mt<2;++mt)
    #pragma unroll
    for(int nt=0;nt<2;++nt){
      int n = nt*32 + l31;
      const float* bp = bias + h*4096 + n*64 + mt*32 + 4*hi;
      #pragma unroll
      for(int q=0;q<4;++q){
        float4 bv = *(const float4*)(bp + q*8);
        S[mt][nt][4*q+0] = bv.x; S[mt][nt][4*q+1] = bv.y;
        S[mt][nt][4*q+2] = bv.z; S[mt][nt][4*q+3] = bv.w;
      }
    }
  __builtin_amdgcn_s_setprio(1);
  #pragma unroll
  for(int ks=0;ks<2;++ks)
    #pragma unroll
    for(int mt=0;mt<2;++mt)
      #pragma unroll
      for(int nt=0;nt<2;++nt)
        S[mt][nt] = __builtin_amdgcn_mfma_f32_32x32x16_bf16(kf[mt][ks], qf[nt][ks], S[mt][nt], 0,0,0);
  __builtin_amdgcn_s_setprio(0);

  float rs[2];
  u32 cb0[2][8], cb1[2][8];
  #pragma unroll
  for(int nt=0;nt<2;++nt){
    float t[16];
    #pragma unroll
    for(int j=0;j<16;++j) t[j] = fmaxf(S[0][nt][j], S[1][nt][j]);
    #pragma unroll
    for(int s=8;s>0;s>>=1)
      #pragma unroll
      for(int j=0;j<8;++j) if(j<s) t[j] = fmaxf(t[j], t[j+s]);
    float mx = fmaxf(t[0], __shfl_xor(t[0], 32));
    float sm[16];
    #pragma unroll
    for(int j=0;j<16;++j){
      S[0][nt][j] = __builtin_amdgcn_exp2f(S[0][nt][j] - mx);
      S[1][nt][j] = __builtin_amdgcn_exp2f(S[1][nt][j] - mx);
      sm[j] = S[0][nt][j] + S[1][nt][j];
    }
    #pragma unroll
    for(int s=8;s>0;s>>=1)
      #pragma unroll
      for(int j=0;j<8;++j) if(j<s) sm[j] += sm[j+s];
    float total = sm[0] + __shfl_xor(sm[0], 32);
    rs[nt] = 1.0f/total;
    #pragma unroll
    for(int mt=0;mt<2;++mt)
      #pragma unroll
      for(int q=0;q<4;++q){
        cb0[nt][mt*4+q] = pack2(S[mt][nt][4*q+0], S[mt][nt][4*q+1]);
        cb1[nt][mt*4+q] = pack2(S[mt][nt][4*q+2], S[mt][nt][4*q+3]);
      }
  }

  // O^T = V^T · P^T (vf from RB, P built in-register)
  f32x16 O[2];
  O[0] = (f32x16)(0.f); O[1] = (f32x16)(0.f);
  __builtin_amdgcn_s_setprio(1);
  #pragma unroll
  for(int ks2=0;ks2<4;++ks2){
    bf16x8 vf = *(const bf16x8*)(RB + (((h*32 + l31)*128 + (ks2*16 + hi*8)*2) ^ ((l31&7)<<4)));
    #pragma unroll
    for(int nt=0;nt<2;++nt){
      u32 A0 = cb0[nt][2*ks2], B0 = cb0[nt][2*ks2+1];
      u32 A1 = cb1[nt][2*ks2], B1 = cb1[nt][2*ks2+1];
      u32 r0 = (u32)__shfl_xor((int)(hi ? A0 : B0), 32);
      u32 r1 = (u32)__shfl_xor((int)(hi ? A1 : B1), 32);
      u32 w0 = hi ? r0 : A0;
      u32 w1 = hi ? r1 : A1;
      u32 w2 = hi ? B0 : r0;
      u32 w3 = hi ? B1 : r1;
      UV t; t.u = (u32x4v){w0,w1,w2,w3};
      O[nt] = __builtin_amdgcn_mfma_f32_32x32x16_bf16(vf, t.v, O[nt], 0,0,0);
    }
  }
  __builtin_amdgcn_s_setprio(0);

  // ---------- T14: stage next window's x into RA (free since kf barrier); latency hides under epilogue+proj ----------
  if(STAGE_NEXT) stage_x(xn, RA, tid);

  // epilogue: scale by 1/rowsum, pack, store ao chunk h (overwrites own vT chunk)
  #pragma unroll
  for(int nt=0;nt<2;++nt){
    int n = nt*32 + l31;
    #pragma unroll
    for(int q=0;q<4;++q){
      u32x2v d;
      d[0] = pack2(O[nt][4*q+0]*rs[nt], O[nt][4*q+1]*rs[nt]);
      d[1] = pack2(O[nt][4*q+2]*rs[nt], O[nt][4*q+3]*rs[nt]);
      *(u32x2v*)(RB + h*4096 + ((n*64 + (8*q + 4*hi)*2) ^ ((n&7)<<4))) = d;
    }
  }
  __syncthreads();   // ao visible (+ staged next-x visible)

  // ---------- proj GEMM: wave w -> out cols w*32..w*32+31 ----------
  {
    f32x4 pacc[4][2];
    #pragma unroll
    for(int ct=0;ct<2;++ct){
      float bv = proj_b[w*32 + ct*16 + li];
      #pragma unroll
      for(int rt=0;rt<4;++rt) pacc[rt][ct] = (f32x4){bv,bv,bv,bv};
    }
    const u16* pbase = pjw + (w*32 + li)*256 + g*8;    // + ct*4096 + ks*32
    bf16x8 bc[2];
    #pragma unroll
    for(int ct=0;ct<2;++ct) bc[ct] = *(const bf16x8*)(pbase + ct*4096);
    __builtin_amdgcn_s_setprio(1);
    #pragma unroll
    for(int ks=0;ks<8;++ks){   // K-chunk ks = ao head-chunk ks
      bf16x8 a[4];
      #pragma unroll
      for(int rt=0;rt<4;++rt){
        int row = rt*16 + li;
        a[rt] = *(const bf16x8*)(RB + ks*4096 + ((row*64 + g*16) ^ ((row&7)<<4)));
      }
      #pragma unroll
      for(int ct=0;ct<2;++ct){
        #pragma unroll
        for(int rt=0;rt<4;++rt)
          pacc[rt][ct] = __builtin_amdgcn_mfma_f32_16x16x32_bf16(a[rt], bc[ct], pacc[rt][ct], 0,0,0);
        if(ks<7) bc[ct] = *(const bf16x8*)(pbase + ct*4096 + (ks+1)*32);   // prefetch
      }
    }
    __builtin_amdgcn_s_setprio(0);
    #pragma unroll
    for(int rt=0;rt<4;++rt)
      #pragma unroll
      for(int ct=0;ct<2;++ct)
        #pragma unroll
        for(int r=0;r<4;++r)
          out[(bw*64 + rt*16 + 4*g + r)*256 + w*32 + ct*16 + li] = pacc[rt][ct][r];
  }
}

// ---------------- Fused kernel: 2 windows per block, straight-line ----------------
__global__ __launch_bounds__(512,4) void k_fused(const float* __restrict__ x, const u16* __restrict__ kvw,
                                                 const float* __restrict__ kv_b, const u16* __restrict__ q_s,
                                                 const float* __restrict__ bias, const u16* __restrict__ pjw,
                                                 const float* __restrict__ proj_b, float* __restrict__ out){
  __shared__ char smem[65536];
  char* RA = smem;
  char* RB = smem + 32768;

  const int tid = threadIdx.x;
  const int w = tid>>6, l = tid&63, g = l>>4, li = l&15;
  const int l31 = l&31, hi = l>>5;
  const int oddl = li & 1;

  const int vw = blockIdx.x*2;
  const int b0=vw>>8,   h10=(vw>>4)&15,   w10=vw&15;
  const int vn = vw+1;
  const int b1=vn>>8,   h11=(vn>>4)&15,   w11=vn&15;
  const float* x0 = x + b0*4194304 + h10*262144 + w10*2048;
  const float* x1 = x + b1*4194304 + h11*262144 + w11*2048;

  stage_x(x0, RA, tid);
  __syncthreads();

  do_window<true >(vw, x1, RA, RB, kvw, kv_b, q_s, bias, pjw, proj_b, out,
                   tid, w, g, li, l31, hi, oddl);
  __syncthreads();   // proj(w0) reads of RB drained -> RB free for w1's vT; RA already holds w1's x

  do_window<false>(vn, nullptr, RA, RB, kvw, kv_b, q_s, bias, pjw, proj_b, out,
                   tid, w, g, li, l31, hi, oddl);
}

extern "C" void kernel_launch(void* const* d_in, const int* in_sizes, int n_in,
                              void* d_out, int out_size, void* d_ws, size_t ws_size,
                              hipStream_t stream){
  (void)in_sizes; (void)n_in; (void)out_size;
  const float* x      = (const float*)d_in[0];
  const float* emb    = (const float*)d_in[1];
  const float* rpb    = (const float*)d_in[2];
  const float* q_w    = (const float*)d_in[3];
  const float* q_b    = (const float*)d_in[4];
  const float* kv_w   = (const float*)d_in[5];
  const float* kv_b   = (const float*)d_in[6];
  const float* proj_w = (const float*)d_in[7];
  const float* proj_b = (const float*)d_in[8];
  float* out = (float*)d_out;

  // ws layout (bytes): q_s 32K | bias 128K | kvw_bf 256K | pjw_bf 128K
  char* ws = (char*)d_ws;
  if(ws_size < (size_t)557056) return;   // diagnostic: out stays zero if ws too small
  u16* q_s   = (u16*)(ws);
  float* bias= (float*)(ws + 32768);
  u32* kvb   = (u32*)(ws + 163840);
  u32* pjb   = (u32*)(ws + 425984);

  k_prep <<< 576, 256, 0, stream>>>(emb, q_w, q_b, q_s, rpb, bias, kv_w, proj_w, kvb, pjb);
  k_fused<<<1024, 512, 0, stream>>>(x, (const u16*)kvb, kv_b, q_s, bias,
                                    (const u16*)pjb, proj_b, out);
}

// Round 10
// 356.818 us; speedup vs baseline: 1.1204x; 1.1204x over previous
//
#include <hip/hip_runtime.h>

typedef short bf16x8 __attribute__((ext_vector_type(8)));
typedef float f32x4 __attribute__((ext_vector_type(4)));
typedef float f32x16 __attribute__((ext_vector_type(16)));
typedef unsigned u32;
typedef unsigned short u16;
typedef unsigned u32x4v __attribute__((ext_vector_type(4)));
typedef unsigned u32x2v __attribute__((ext_vector_type(2)));

union UV { u32x4v u; bf16x8 v; };

__device__ __forceinline__ u16 f2bf(float f){          // RNE fp32->bf16 (cold paths)
  u32 u = __float_as_uint(f);
  u += 0x7FFFu + ((u>>16)&1u);
  return (u16)(u>>16);
}
// hot-path pair conversion: single v_cvt_pk_bf16_f32 (no builtin on gfx950 -> inline asm, T12 recipe)
__device__ __forceinline__ u32 pack2(float lo, float hi){
  u32 r;
  asm("v_cvt_pk_bf16_f32 %0, %1, %2" : "=v"(r) : "v"(lo), "v"(hi));
  return r;
}

#define LOG2E 1.4426950408889634f

// ---------------- K_prep: fused prologue (q_scaled | bias | weight cvt) ----------------
__global__ void k_prep(const float* __restrict__ emb, const float* __restrict__ q_w,
                       const float* __restrict__ q_b, u16* __restrict__ q_s,
                       const float* __restrict__ rpb, float* __restrict__ bias,
                       const float* __restrict__ kv_w, const float* __restrict__ proj_w,
                       u32* __restrict__ kvb, u32* __restrict__ pjb){
  const int blk = blockIdx.x, tid = threadIdx.x;
  if(blk < 64){
    const int n = blk, d = tid;
    const float4* er = (const float4*)(emb + n*256);
    const float4* wr = (const float4*)(q_w + d*256);
    float acc = 0.f;
    for(int c=0;c<64;++c){
      float4 e = er[c], w = wr[c];
      acc += e.x*w.x + e.y*w.y + e.z*w.z + e.w*w.w;
    }
    acc += q_b[d];
    q_s[n*256 + d] = f2bf(acc * (0.17677669529663687f * LOG2E));   // 32^-0.5 * log2e
  } else if(blk < 192){
    const int o = (blk-64)*256 + tid;          // 32768
    const int h = o>>12, n = (o>>6)&63, m = o&63;
    const int idx = ((n>>3)-(m>>3)+7)*15 + ((n&7)-(m&7)+7);
    bias[o] = rpb[idx*8 + h] * LOG2E;
  } else {
    const int i = (blk-192)*256 + tid;         // 98304
    if(i < 65536) kvb[i] = pack2(kv_w[2*i], kv_w[2*i+1]);
    else { int j = i - 65536; pjb[j] = pack2(proj_w[2*j], proj_w[2*j+1]); }
  }
}

// ---------------- Fused per-window kernel, 8 waves, one head per wave ----------------
// Two LDS regions (R8 structure + merged publish):
//   RA (32KB): x_bf16[64 tok][256 ch] swz -> k[64 tok][256 ch] swz   (never rewritten after)
//   RB (32KB): vT[8 h][32 e][64 m] swz -> ao[8 h][64 n][32 e] swz    (own-head chunk overwrite)
// swizzles: row-major tiles use byte ^= ((row&7)<<4)
// Barriers: post-stage, post-KV, post-publish, post-ao  (4 total; R8 had 6)
__global__ __launch_bounds__(512,4) void k_fused(const float* __restrict__ x, const u16* __restrict__ kvw,
                                                 const float* __restrict__ kv_b, const u16* __restrict__ q_s,
                                                 const float* __restrict__ bias, const u16* __restrict__ pjw,
                                                 const float* __restrict__ proj_b, float* __restrict__ out){
  __shared__ char smem[65536];
  char* RA = smem;
  char* RB = smem + 32768;

  const int bw = blockIdx.x;
  const int b = bw>>8, h1 = (bw>>4)&15, w1 = bw&15;
  const int base = b*4194304 + h1*262144 + w1*2048;
  const int tid = threadIdx.x;
  const int w = tid>>6, l = tid&63, g = l>>4, li = l&15;
  const int l31 = l&31, hi = l>>5;

  // ---------- Phase 0: cooperative stage x window -> RA as bf16 (swizzled) ----------
  #pragma unroll
  for(int i=0;i<4;++i){
    int p = i*512 + tid;                 // 16B-pair index 0..2047
    int n = p>>5;                        // token row 0..63
    int c4 = (2*p)&63;                   // f4 index within row (even)
    const float4* gp = (const float4*)(x + base + (n>>3)*32768 + (n&7)*256 + c4*4);
    float4 lo = gp[0], hh = gp[1];
    u32x4v d = { pack2(lo.x,lo.y), pack2(lo.z,lo.w), pack2(hh.x,hh.y), pack2(hh.z,hh.w) };
    *(u32x4v*)(RA + ((p*16) ^ ((n&7)<<4))) = d;
  }
  __syncthreads();

  // ---------- Phase 1: KV GEMM. wave w computes output cols w*64..w*64+63 ----------
  f32x4 acc[4][4];
  #pragma unroll
  for(int ct=0;ct<4;++ct){
    float bv = kv_b[w*64 + ct*16 + li];
    #pragma unroll
    for(int rt=0;rt<4;++rt) acc[rt][ct] = (f32x4){bv,bv,bv,bv};
  }
  {
    const u16* wbase = kvw + (w*64 + li)*256 + g*8;   // + ct*4096 + ks*32
    bf16x8 bcur[4];
    #pragma unroll
    for(int ct=0;ct<4;++ct) bcur[ct] = *(const bf16x8*)(wbase + ct*4096);
    __builtin_amdgcn_s_setprio(1);
    #pragma unroll
    for(int ks=0;ks<8;++ks){
      bf16x8 a[4];
      #pragma unroll
      for(int rt=0;rt<4;++rt){
        int n = rt*16 + li;
        a[rt] = *(const bf16x8*)(RA + ((n*512 + ks*64 + g*16) ^ ((n&7)<<4)));
      }
      #pragma unroll
      for(int ct=0;ct<4;++ct){
        #pragma unroll
        for(int rt=0;rt<4;++rt)
          acc[rt][ct] = __builtin_amdgcn_mfma_f32_16x16x32_bf16(a[rt], bcur[ct], acc[rt][ct], 0,0,0);
        if(ks<7) bcur[ct] = *(const bf16x8*)(wbase + ct*4096 + (ks+1)*32);  // load-after-use prefetch
      }
    }
    __builtin_amdgcn_s_setprio(0);
  }
  __syncthreads();   // x image dead -> RA free for k

  // qf prefetch (global, window-independent; B-frag for 32x32x16)
  const int h = w;   // this wave's head
  bf16x8 qf[2][2];
  #pragma unroll
  for(int nt=0;nt<2;++nt)
    #pragma unroll
    for(int ks=0;ks<2;++ks)
      qf[nt][ks] = *(const bf16x8*)(q_s + (nt*32 + l31)*256 + h*32 + ks*16 + hi*8);

  // ---------- Phase 2: merged publish — waves 0..3 -> k into RA | waves 4..7 -> vT into RB ----------
  const int oddl = li & 1;
  if(w < 4){
    #pragma unroll
    for(int ct=0;ct<4;++ct){
      int colp = w*64 + ct*16 + (li & ~1);   // even col of the pair
      #pragma unroll
      for(int rt=0;rt<4;++rt){
        float v0=acc[rt][ct][0], v1=acc[rt][ct][1], v2=acc[rt][ct][2], v3=acc[rt][ct][3];
        float o0=__shfl_xor(v0,1), o1=__shfl_xor(v1,1), o2=__shfl_xor(v2,1), o3=__shfl_xor(v3,1);
        u32 d0 = oddl ? pack2(o2,v2) : pack2(v0,o0);
        u32 d1 = oddl ? pack2(o3,v3) : pack2(v1,o1);
        int row0 = rt*16 + 4*g + (oddl ? 2 : 0);
        *(u32*)(RA + ((row0*512     + colp*2) ^ ((row0&7)<<4)))     = d0;
        *(u32*)(RA + (((row0+1)*512 + colp*2) ^ (((row0+1)&7)<<4))) = d1;
      }
    }
  } else {
    #pragma unroll
    for(int ct=0;ct<4;++ct){
      int c2 = (w-4)*64 + ct*16 + li;     // 0..255
      int hv = c2>>5, e = c2&31;
      #pragma unroll
      for(int rt=0;rt<4;++rt){
        u32x2v d;
        d[0] = pack2(acc[rt][ct][0], acc[rt][ct][1]);
        d[1] = pack2(acc[rt][ct][2], acc[rt][ct][3]);
        int m0 = rt*16 + 4*g;
        *(u32x2v*)(RB + (((hv*32 + e)*128 + m0*2) ^ ((e&7)<<4))) = d;
      }
    }
  }
  __syncthreads();   // k and vT visible

  // ---------- Phase 3: kf preload from RA (no trailing barrier — RA is never rewritten) ----------
  bf16x8 kf[2][2];
  #pragma unroll
  for(int mt=0;mt<2;++mt)
    #pragma unroll
    for(int ks=0;ks<2;++ks){
      int row = mt*32 + l31;
      kf[mt][ks] = *(const bf16x8*)(RA + ((row*512 + (h*32 + ks*16 + hi*8)*2) ^ ((row&7)<<4)));
    }

  // ---------- attention: S^T = K·Q^T (32x32 tiles), softmax in log2 units ----------
  f32x16 S[2][2];
  #pragma unroll
  for(int mt=0;mt<2;++mt)
    #pragma unroll
    for(int nt=0;nt<2;++nt){
      int n = nt*32 + l31;
      const float* bp = bias + h*4096 + n*64 + mt*32 + 4*hi;
      #pragma unroll
      for(int q=0;q<4;++q){
        float4 bv = *(const float4*)(bp + q*8);
        S[mt][nt][4*q+0] = bv.x; S[mt][nt][4*q+1] = bv.y;
        S[mt][nt][4*q+2] = bv.z; S[mt][nt][4*q+3] = bv.w;
      }
    }
  __builtin_amdgcn_s_setprio(1);
  #pragma unroll
  for(int ks=0;ks<2;++ks)
    #pragma unroll
    for(int mt=0;mt<2;++mt)
      #pragma unroll
      for(int nt=0;nt<2;++nt)
        S[mt][nt] = __builtin_amdgcn_mfma_f32_32x32x16_bf16(kf[mt][ks], qf[nt][ks], S[mt][nt], 0,0,0);
  __builtin_amdgcn_s_setprio(0);

  // softmax over m (rows of S^T): 32 local values + partner lane (l^32); S is in log2-units
  float rs[2];
  u32 cb0[2][8], cb1[2][8];
  #pragma unroll
  for(int nt=0;nt<2;++nt){
    float t[16];
    #pragma unroll
    for(int j=0;j<16;++j) t[j] = fmaxf(S[0][nt][j], S[1][nt][j]);
    #pragma unroll
    for(int s=8;s>0;s>>=1)
      #pragma unroll
      for(int j=0;j<8;++j) if(j<s) t[j] = fmaxf(t[j], t[j+s]);
    float mx = fmaxf(t[0], __shfl_xor(t[0], 32));
    float sm[16];
    #pragma unroll
    for(int j=0;j<16;++j){
      S[0][nt][j] = __builtin_amdgcn_exp2f(S[0][nt][j] - mx);
      S[1][nt][j] = __builtin_amdgcn_exp2f(S[1][nt][j] - mx);
      sm[j] = S[0][nt][j] + S[1][nt][j];
    }
    #pragma unroll
    for(int s=8;s>0;s>>=1)
      #pragma unroll
      for(int j=0;j<8;++j) if(j<s) sm[j] += sm[j+s];
    float total = sm[0] + __shfl_xor(sm[0], 32);
    rs[nt] = 1.0f/total;
    // pack P to bf16 pairs: block b = mt*4+q holds m = 32mt+8q+4hi + {0..3}
    #pragma unroll
    for(int mt=0;mt<2;++mt)
      #pragma unroll
      for(int q=0;q<4;++q){
        cb0[nt][mt*4+q] = pack2(S[mt][nt][4*q+0], S[mt][nt][4*q+1]);
        cb1[nt][mt*4+q] = pack2(S[mt][nt][4*q+2], S[mt][nt][4*q+3]);
      }
  }

  // O^T = V^T · P^T : A-frag vf from RB (row e = l31, k m = ks2*16+hi*8+j), B-frag built in-register
  f32x16 O[2];
  O[0] = (f32x16)(0.f); O[1] = (f32x16)(0.f);
  __builtin_amdgcn_s_setprio(1);
  #pragma unroll
  for(int ks2=0;ks2<4;++ks2){
    bf16x8 vf = *(const bf16x8*)(RB + (((h*32 + l31)*128 + (ks2*16 + hi*8)*2) ^ ((l31&7)<<4)));
    #pragma unroll
    for(int nt=0;nt<2;++nt){
      u32 A0 = cb0[nt][2*ks2], B0 = cb0[nt][2*ks2+1];
      u32 A1 = cb1[nt][2*ks2], B1 = cb1[nt][2*ks2+1];
      u32 r0 = (u32)__shfl_xor((int)(hi ? A0 : B0), 32);
      u32 r1 = (u32)__shfl_xor((int)(hi ? A1 : B1), 32);
      u32 w0 = hi ? r0 : A0;
      u32 w1 = hi ? r1 : A1;
      u32 w2 = hi ? B0 : r0;
      u32 w3 = hi ? B1 : r1;
      UV t; t.u = (u32x4v){w0,w1,w2,w3};
      O[nt] = __builtin_amdgcn_mfma_f32_32x32x16_bf16(vf, t.v, O[nt], 0,0,0);
    }
  }
  __builtin_amdgcn_s_setprio(0);

  // epilogue: scale by 1/rowsum, pack, store ao chunk h into RB (own vT chunk; per-wave LDS ops are in-order)
  #pragma unroll
  for(int nt=0;nt<2;++nt){
    int n = nt*32 + l31;
    #pragma unroll
    for(int q=0;q<4;++q){
      u32x2v d;
      d[0] = pack2(O[nt][4*q+0]*rs[nt], O[nt][4*q+1]*rs[nt]);
      d[1] = pack2(O[nt][4*q+2]*rs[nt], O[nt][4*q+3]*rs[nt]);
      *(u32x2v*)(RB + h*4096 + ((n*64 + (8*q + 4*hi)*2) ^ ((n&7)<<4))) = d;
    }
  }
  __syncthreads();   // ao visible

  // ---------- Phase 4: proj GEMM. wave w -> out cols w*32..w*32+31 ----------
  {
    f32x4 pacc[4][2];
    #pragma unroll
    for(int ct=0;ct<2;++ct){
      float bv = proj_b[w*32 + ct*16 + li];
      #pragma unroll
      for(int rt=0;rt<4;++rt) pacc[rt][ct] = (f32x4){bv,bv,bv,bv};
    }
    const u16* pbase = pjw + (w*32 + li)*256 + g*8;    // + ct*4096 + ks*32
    bf16x8 bc[2];
    #pragma unroll
    for(int ct=0;ct<2;++ct) bc[ct] = *(const bf16x8*)(pbase + ct*4096);
    __builtin_amdgcn_s_setprio(1);
    #pragma unroll
    for(int ks=0;ks<8;++ks){   // K-chunk ks = ao head-chunk ks (32 chans per head)
      bf16x8 a[4];
      #pragma unroll
      for(int rt=0;rt<4;++rt){
        int row = rt*16 + li;
        a[rt] = *(const bf16x8*)(RB + ks*4096 + ((row*64 + g*16) ^ ((row&7)<<4)));
      }
      #pragma unroll
      for(int ct=0;ct<2;++ct){
        #pragma unroll
        for(int rt=0;rt<4;++rt)
          pacc[rt][ct] = __builtin_amdgcn_mfma_f32_16x16x32_bf16(a[rt], bc[ct], pacc[rt][ct], 0,0,0);
        if(ks<7) bc[ct] = *(const bf16x8*)(pbase + ct*4096 + (ks+1)*32);   // load-after-use prefetch
      }
    }
    __builtin_amdgcn_s_setprio(0);
    #pragma unroll
    for(int rt=0;rt<4;++rt)
      #pragma unroll
      for(int ct=0;ct<2;++ct)
        #pragma unroll
        for(int r=0;r<4;++r)
          out[(bw*64 + rt*16 + 4*g + r)*256 + w*32 + ct*16 + li] = pacc[rt][ct][r];
  }
}

extern "C" void kernel_launch(void* const* d_in, const int* in_sizes, int n_in,
                              void* d_out, int out_size, void* d_ws, size_t ws_size,
                              hipStream_t stream){
  (void)in_sizes; (void)n_in; (void)out_size;
  const float* x      = (const float*)d_in[0];
  const float* emb    = (const float*)d_in[1];
  const float* rpb    = (const float*)d_in[2];
  const float* q_w    = (const float*)d_in[3];
  const float* q_b    = (const float*)d_in[4];
  const float* kv_w   = (const float*)d_in[5];
  const float* kv_b   = (const float*)d_in[6];
  const float* proj_w = (const float*)d_in[7];
  const float* proj_b = (const float*)d_in[8];
  float* out = (float*)d_out;

  // ws layout (bytes): q_s 32K | bias 128K | kvw_bf 256K | pjw_bf 128K
  char* ws = (char*)d_ws;
  if(ws_size < (size_t)557056) return;   // diagnostic: out stays zero if ws too small
  u16* q_s   = (u16*)(ws);
  float* bias= (float*)(ws + 32768);
  u32* kvb   = (u32*)(ws + 163840);
  u32* pjb   = (u32*)(ws + 425984);

  k_prep <<< 576, 256, 0, stream>>>(emb, q_w, q_b, q_s, rpb, bias, kv_w, proj_w, kvb, pjb);
  k_fused<<<2048, 512, 0, stream>>>(x, (const u16*)kvb, kv_b, q_s, bias,
                                    (const u16*)pjb, proj_b, out);
}

// Round 11
// 352.624 us; speedup vs baseline: 1.1338x; 1.0119x over previous
//
#include <hip/hip_runtime.h>

typedef short bf16x8 __attribute__((ext_vector_type(8)));
typedef float f32x4 __attribute__((ext_vector_type(4)));
typedef float f32x16 __attribute__((ext_vector_type(16)));
typedef unsigned u32;
typedef unsigned short u16;
typedef unsigned u32x4v __attribute__((ext_vector_type(4)));
typedef unsigned u32x2v __attribute__((ext_vector_type(2)));

union UV { u32x4v u; bf16x8 v; };

__device__ __forceinline__ u16 f2bf(float f){          // RNE fp32->bf16 (cold paths)
  u32 u = __float_as_uint(f);
  u += 0x7FFFu + ((u>>16)&1u);
  return (u16)(u>>16);
}
// hot-path pair conversion: single v_cvt_pk_bf16_f32 (no builtin on gfx950 -> inline asm, T12 recipe)
__device__ __forceinline__ u32 pack2(float lo, float hi){
  u32 r;
  asm("v_cvt_pk_bf16_f32 %0, %1, %2" : "=v"(r) : "v"(lo), "v"(hi));
  return r;
}

#define LOG2E 1.4426950408889634f

// ---------------- K_prep: fused prologue (q_scaled | bias | weight cvt) ----------------
__global__ void k_prep(const float* __restrict__ emb, const float* __restrict__ q_w,
                       const float* __restrict__ q_b, u16* __restrict__ q_s,
                       const float* __restrict__ rpb, float* __restrict__ bias,
                       const float* __restrict__ kv_w, const float* __restrict__ proj_w,
                       u32* __restrict__ kvb, u32* __restrict__ pjb){
  const int blk = blockIdx.x, tid = threadIdx.x;
  if(blk < 64){
    const int n = blk, d = tid;
    const float4* er = (const float4*)(emb + n*256);
    const float4* wr = (const float4*)(q_w + d*256);
    float acc = 0.f;
    for(int c=0;c<64;++c){
      float4 e = er[c], w = wr[c];
      acc += e.x*w.x + e.y*w.y + e.z*w.z + e.w*w.w;
    }
    acc += q_b[d];
    q_s[n*256 + d] = f2bf(acc * (0.17677669529663687f * LOG2E));   // 32^-0.5 * log2e
  } else if(blk < 192){
    const int o = (blk-64)*256 + tid;          // 32768
    const int h = o>>12, n = (o>>6)&63, m = o&63;
    const int idx = ((n>>3)-(m>>3)+7)*15 + ((n&7)-(m&7)+7);
    bias[o] = rpb[idx*8 + h] * LOG2E;
  } else {
    const int i = (blk-192)*256 + tid;         // 98304
    if(i < 65536) kvb[i] = pack2(kv_w[2*i], kv_w[2*i+1]);
    else { int j = i - 65536; pjb[j] = pack2(proj_w[2*j], proj_w[2*j+1]); }
  }
}

// ---------------- Fused per-window kernel, 8 waves, one head per wave ----------------
// Two LDS regions:
//   RA (32KB): x_bf16[64 tok][256 ch] swz -> k[64 tok][256 ch] swz   (never rewritten after)
//   RB (32KB): vT[8 h][32 e][64 m] swz -> ao[8 h][64 n][32 e] swz    (own-head chunk overwrite)
// swizzles: row-major tiles use byte ^= ((row&7)<<4)
// Barriers: post-stage, post-KV, post-publish, post-ao (4 total)
__global__ __launch_bounds__(512,4) void k_fused(const float* __restrict__ x, const u16* __restrict__ kvw,
                                                 const float* __restrict__ kv_b, const u16* __restrict__ q_s,
                                                 const float* __restrict__ bias, const u16* __restrict__ pjw,
                                                 const float* __restrict__ proj_b, float* __restrict__ out){
  __shared__ char smem[65536];
  char* RA = smem;
  char* RB = smem + 32768;

  const int bw = blockIdx.x;
  const int b = bw>>8, h1 = (bw>>4)&15, w1 = bw&15;
  const int base = b*4194304 + h1*262144 + w1*2048;
  const int tid = threadIdx.x;
  const int w = tid>>6, l = tid&63, g = l>>4, li = l&15;
  const int l31 = l&31, hi = l>>5;

  // KV weight preload hoisted ABOVE stage: its L2 latency hides under the stage HBM wait
  const u16* wbase = kvw + (w*64 + li)*256 + g*8;   // + ct*4096 + ks*32
  bf16x8 bcur[4];
  #pragma unroll
  for(int ct=0;ct<4;++ct) bcur[ct] = *(const bf16x8*)(wbase + ct*4096);

  // ---------- Phase 0: cooperative stage x window -> RA as bf16 (swizzled; nontemporal reads) ----------
  #pragma unroll
  for(int i=0;i<4;++i){
    int p = i*512 + tid;                 // 16B-pair index 0..2047
    int n = p>>5;                        // token row 0..63
    int c4 = (2*p)&63;                   // f4 index within row (even)
    const f32x4* gp = (const f32x4*)(x + base + (n>>3)*32768 + (n&7)*256 + c4*4);
    f32x4 lo = __builtin_nontemporal_load(gp);
    f32x4 hh = __builtin_nontemporal_load(gp+1);
    u32x4v d = { pack2(lo[0],lo[1]), pack2(lo[2],lo[3]), pack2(hh[0],hh[1]), pack2(hh[2],hh[3]) };
    *(u32x4v*)(RA + ((p*16) ^ ((n&7)<<4))) = d;
  }
  __syncthreads();

  // ---------- Phase 1: KV GEMM. wave w computes output cols w*64..w*64+63 ----------
  f32x4 acc[4][4];
  #pragma unroll
  for(int ct=0;ct<4;++ct){
    float bv = kv_b[w*64 + ct*16 + li];
    #pragma unroll
    for(int rt=0;rt<4;++rt) acc[rt][ct] = (f32x4){bv,bv,bv,bv};
  }
  {
    __builtin_amdgcn_s_setprio(1);
    #pragma unroll
    for(int ks=0;ks<8;++ks){
      bf16x8 a[4];
      #pragma unroll
      for(int rt=0;rt<4;++rt){
        int n = rt*16 + li;
        a[rt] = *(const bf16x8*)(RA + ((n*512 + ks*64 + g*16) ^ ((n&7)<<4)));
      }
      #pragma unroll
      for(int ct=0;ct<4;++ct){
        #pragma unroll
        for(int rt=0;rt<4;++rt)
          acc[rt][ct] = __builtin_amdgcn_mfma_f32_16x16x32_bf16(a[rt], bcur[ct], acc[rt][ct], 0,0,0);
        if(ks<7) bcur[ct] = *(const bf16x8*)(wbase + ct*4096 + (ks+1)*32);  // load-after-use prefetch
      }
    }
    __builtin_amdgcn_s_setprio(0);
  }
  __syncthreads();   // x image dead -> RA free for k

  // qf prefetch (global, window-independent; B-frag for 32x32x16)
  const int h = w;   // this wave's head
  bf16x8 qf[2][2];
  #pragma unroll
  for(int nt=0;nt<2;++nt)
    #pragma unroll
    for(int ks=0;ks<2;++ks)
      qf[nt][ks] = *(const bf16x8*)(q_s + (nt*32 + l31)*256 + h*32 + ks*16 + hi*8);

  // ---------- Phase 2: merged publish — waves 0..3 -> k into RA | waves 4..7 -> vT into RB ----------
  const int oddl = li & 1;
  if(w < 4){
    #pragma unroll
    for(int ct=0;ct<4;++ct){
      int colp = w*64 + ct*16 + (li & ~1);   // even col of the pair
      #pragma unroll
      for(int rt=0;rt<4;++rt){
        float v0=acc[rt][ct][0], v1=acc[rt][ct][1], v2=acc[rt][ct][2], v3=acc[rt][ct][3];
        float o0=__shfl_xor(v0,1), o1=__shfl_xor(v1,1), o2=__shfl_xor(v2,1), o3=__shfl_xor(v3,1);
        u32 d0 = oddl ? pack2(o2,v2) : pack2(v0,o0);
        u32 d1 = oddl ? pack2(o3,v3) : pack2(v1,o1);
        int row0 = rt*16 + 4*g + (oddl ? 2 : 0);
        *(u32*)(RA + ((row0*512     + colp*2) ^ ((row0&7)<<4)))     = d0;
        *(u32*)(RA + (((row0+1)*512 + colp*2) ^ (((row0+1)&7)<<4))) = d1;
      }
    }
  } else {
    #pragma unroll
    for(int ct=0;ct<4;++ct){
      int c2 = (w-4)*64 + ct*16 + li;     // 0..255
      int hv = c2>>5, e = c2&31;
      #pragma unroll
      for(int rt=0;rt<4;++rt){
        u32x2v d;
        d[0] = pack2(acc[rt][ct][0], acc[rt][ct][1]);
        d[1] = pack2(acc[rt][ct][2], acc[rt][ct][3]);
        int m0 = rt*16 + 4*g;
        *(u32x2v*)(RB + (((hv*32 + e)*128 + m0*2) ^ ((e&7)<<4))) = d;
      }
    }
  }
  __syncthreads();   // k and vT visible

  // ---------- Phase 3: kf preload from RA (no trailing barrier — RA is never rewritten) ----------
  bf16x8 kf[2][2];
  #pragma unroll
  for(int mt=0;mt<2;++mt)
    #pragma unroll
    for(int ks=0;ks<2;++ks){
      int row = mt*32 + l31;
      kf[mt][ks] = *(const bf16x8*)(RA + ((row*512 + (h*32 + ks*16 + hi*8)*2) ^ ((row&7)<<4)));
    }

  // ---------- attention: S^T = K·Q^T (32x32 tiles), softmax in log2 units ----------
  f32x16 S[2][2];
  #pragma unroll
  for(int mt=0;mt<2;++mt)
    #pragma unroll
    for(int nt=0;nt<2;++nt){
      int n = nt*32 + l31;
      const float* bp = bias + h*4096 + n*64 + mt*32 + 4*hi;
      #pragma unroll
      for(int q=0;q<4;++q){
        float4 bv = *(const float4*)(bp + q*8);
        S[mt][nt][4*q+0] = bv.x; S[mt][nt][4*q+1] = bv.y;
        S[mt][nt][4*q+2] = bv.z; S[mt][nt][4*q+3] = bv.w;
      }
    }
  __builtin_amdgcn_s_setprio(1);
  #pragma unroll
  for(int ks=0;ks<2;++ks)
    #pragma unroll
    for(int mt=0;mt<2;++mt)
      #pragma unroll
      for(int nt=0;nt<2;++nt)
        S[mt][nt] = __builtin_amdgcn_mfma_f32_32x32x16_bf16(kf[mt][ks], qf[nt][ks], S[mt][nt], 0,0,0);
  __builtin_amdgcn_s_setprio(0);

  // softmax over m (rows of S^T): 32 local values + partner lane (l^32); S is in log2-units
  float rs[2];
  u32 cb0[2][8], cb1[2][8];
  #pragma unroll
  for(int nt=0;nt<2;++nt){
    float t[16];
    #pragma unroll
    for(int j=0;j<16;++j) t[j] = fmaxf(S[0][nt][j], S[1][nt][j]);
    #pragma unroll
    for(int s=8;s>0;s>>=1)
      #pragma unroll
      for(int j=0;j<8;++j) if(j<s) t[j] = fmaxf(t[j], t[j+s]);
    float mx = fmaxf(t[0], __shfl_xor(t[0], 32));
    float sm[16];
    #pragma unroll
    for(int j=0;j<16;++j){
      S[0][nt][j] = __builtin_amdgcn_exp2f(S[0][nt][j] - mx);
      S[1][nt][j] = __builtin_amdgcn_exp2f(S[1][nt][j] - mx);
      sm[j] = S[0][nt][j] + S[1][nt][j];
    }
    #pragma unroll
    for(int s=8;s>0;s>>=1)
      #pragma unroll
      for(int j=0;j<8;++j) if(j<s) sm[j] += sm[j+s];
    float total = sm[0] + __shfl_xor(sm[0], 32);
    rs[nt] = 1.0f/total;
    // pack P to bf16 pairs: block b = mt*4+q holds m = 32mt+8q+4hi + {0..3}
    #pragma unroll
    for(int mt=0;mt<2;++mt)
      #pragma unroll
      for(int q=0;q<4;++q){
        cb0[nt][mt*4+q] = pack2(S[mt][nt][4*q+0], S[mt][nt][4*q+1]);
        cb1[nt][mt*4+q] = pack2(S[mt][nt][4*q+2], S[mt][nt][4*q+3]);
      }
  }

  // O^T = V^T · P^T : A-frag vf from RB (row e = l31, k m = ks2*16+hi*8+j), B-frag built in-register
  f32x16 O[2];
  O[0] = (f32x16)(0.f); O[1] = (f32x16)(0.f);
  __builtin_amdgcn_s_setprio(1);
  #pragma unroll
  for(int ks2=0;ks2<4;++ks2){
    bf16x8 vf = *(const bf16x8*)(RB + (((h*32 + l31)*128 + (ks2*16 + hi*8)*2) ^ ((l31&7)<<4)));
    #pragma unroll
    for(int nt=0;nt<2;++nt){
      u32 A0 = cb0[nt][2*ks2], B0 = cb0[nt][2*ks2+1];
      u32 A1 = cb1[nt][2*ks2], B1 = cb1[nt][2*ks2+1];
      u32 r0 = (u32)__shfl_xor((int)(hi ? A0 : B0), 32);
      u32 r1 = (u32)__shfl_xor((int)(hi ? A1 : B1), 32);
      u32 w0 = hi ? r0 : A0;
      u32 w1 = hi ? r1 : A1;
      u32 w2 = hi ? B0 : r0;
      u32 w3 = hi ? B1 : r1;
      UV t; t.u = (u32x4v){w0,w1,w2,w3};
      O[nt] = __builtin_amdgcn_mfma_f32_32x32x16_bf16(vf, t.v, O[nt], 0,0,0);
    }
  }
  __builtin_amdgcn_s_setprio(0);

  // proj weight preload hoisted ABOVE ao-epilogue: L2 latency hides under the pack/store + barrier
  const u16* pbase = pjw + (w*32 + li)*256 + g*8;    // + ct*4096 + ks*32
  bf16x8 bc[2];
  #pragma unroll
  for(int ct=0;ct<2;++ct) bc[ct] = *(const bf16x8*)(pbase + ct*4096);

  // epilogue: scale by 1/rowsum, pack, store ao chunk h into RB (own vT chunk)
  #pragma unroll
  for(int nt=0;nt<2;++nt){
    int n = nt*32 + l31;
    #pragma unroll
    for(int q=0;q<4;++q){
      u32x2v d;
      d[0] = pack2(O[nt][4*q+0]*rs[nt], O[nt][4*q+1]*rs[nt]);
      d[1] = pack2(O[nt][4*q+2]*rs[nt], O[nt][4*q+3]*rs[nt]);
      *(u32x2v*)(RB + h*4096 + ((n*64 + (8*q + 4*hi)*2) ^ ((n&7)<<4))) = d;
    }
  }
  __syncthreads();   // ao visible

  // ---------- Phase 4: proj GEMM. wave w -> out cols w*32..w*32+31 ----------
  {
    f32x4 pacc[4][2];
    #pragma unroll
    for(int ct=0;ct<2;++ct){
      float bv = proj_b[w*32 + ct*16 + li];
      #pragma unroll
      for(int rt=0;rt<4;++rt) pacc[rt][ct] = (f32x4){bv,bv,bv,bv};
    }
    __builtin_amdgcn_s_setprio(1);
    #pragma unroll
    for(int ks=0;ks<8;++ks){   // K-chunk ks = ao head-chunk ks (32 chans per head)
      bf16x8 a[4];
      #pragma unroll
      for(int rt=0;rt<4;++rt){
        int row = rt*16 + li;
        a[rt] = *(const bf16x8*)(RB + ks*4096 + ((row*64 + g*16) ^ ((row&7)<<4)));
      }
      #pragma unroll
      for(int ct=0;ct<2;++ct){
        #pragma unroll
        for(int rt=0;rt<4;++rt)
          pacc[rt][ct] = __builtin_amdgcn_mfma_f32_16x16x32_bf16(a[rt], bc[ct], pacc[rt][ct], 0,0,0);
        if(ks<7) bc[ct] = *(const bf16x8*)(pbase + ct*4096 + (ks+1)*32);   // load-after-use prefetch
      }
    }
    __builtin_amdgcn_s_setprio(0);
    // nontemporal final stores: out is write-once, keep L2 for weights/q_s/bias
    #pragma unroll
    for(int rt=0;rt<4;++rt)
      #pragma unroll
      for(int ct=0;ct<2;++ct)
        #pragma unroll
        for(int r=0;r<4;++r)
          __builtin_nontemporal_store(pacc[rt][ct][r],
            &out[(bw*64 + rt*16 + 4*g + r)*256 + w*32 + ct*16 + li]);
  }
}

extern "C" void kernel_launch(void* const* d_in, const int* in_sizes, int n_in,
                              void* d_out, int out_size, void* d_ws, size_t ws_size,
                              hipStream_t stream){
  (void)in_sizes; (void)n_in; (void)out_size;
  const float* x      = (const float*)d_in[0];
  const float* emb    = (const float*)d_in[1];
  const float* rpb    = (const float*)d_in[2];
  const float* q_w    = (const float*)d_in[3];
  const float* q_b    = (const float*)d_in[4];
  const float* kv_w   = (const float*)d_in[5];
  const float* kv_b   = (const float*)d_in[6];
  const float* proj_w = (const float*)d_in[7];
  const float* proj_b = (const float*)d_in[8];
  float* out = (float*)d_out;

  // ws layout (bytes): q_s 32K | bias 128K | kvw_bf 256K | pjw_bf 128K
  char* ws = (char*)d_ws;
  if(ws_size < (size_t)557056) return;   // diagnostic: out stays zero if ws too small
  u16* q_s   = (u16*)(ws);
  float* bias= (float*)(ws + 32768);
  u32* kvb   = (u32*)(ws + 163840);
  u32* pjb   = (u32*)(ws + 425984);

  k_prep <<< 576, 256, 0, stream>>>(emb, q_w, q_b, q_s, rpb, bias, kv_w, proj_w, kvb, pjb);
  k_fused<<<2048, 512, 0, stream>>>(x, (const u16*)kvb, kv_b, q_s, bias,
                                    (const u16*)pjb, proj_b, out);
}